// Round 3
// baseline (401.280 us; speedup 1.0000x reference)
//
#include <hip/hip_runtime.h>

using f16x8 = _Float16 __attribute__((ext_vector_type(8)));
using f32x4 = float __attribute__((ext_vector_type(4)));

#define BS      8192
#define IN_DIM  4096
#define NB      64
#define BD      64
#define HID     256
#define OD      64
#define GY      8
#define SLABS   4          // 4 slabs x 256 rows = 1024 rows per WG

__device__ __forceinline__ float gelu_f(float z) {
    // tanh-form GELU via exp2: z * (1 - 1/(exp2(2.302119*(z+0.044715 z^3)) + 1))
    float t = z * z;
    float p = __builtin_fmaf(0.044715f * z, t, z);
    float e = __builtin_amdgcn_exp2f(p * 2.3021193f);
    float r = __builtin_amdgcn_rcpf(e + 1.0f);
    return __builtin_fmaf(-z, r, z);
}

__global__ __launch_bounds__(512, 4) void blockmlp_kernel(
    const float* __restrict__ xg, const float* __restrict__ w1g,
    const float* __restrict__ b1g, const float* __restrict__ w2g,
    const float* __restrict__ b2g, float* __restrict__ outg) {

    // Both weight matrices live in LDS as pre-built, fragment-major MFMA
    // operands: entry e = (tile index)*64 + lane, each 8 f16. Every runtime
    // read is ds_read_b128 at lds[(e0+l)*16B] -> wave reads 1024 contiguous
    // bytes -> zero bank conflicts.
    __shared__ _Float16 W1F[2048 * 8];   // 32 KB  [ht=16][ks=2][lane][8]
    __shared__ _Float16 W2L[2048 * 8];   // 32 KB  [p=8][n2=4][lane][8]
    __shared__ float    b1L[HID];        // 1 KB

    const int tid = threadIdx.x;
    const int w   = tid >> 6;
    const int l   = tid & 63;
    const int g   = l >> 4;
    const int l15 = l & 15;
    const int n   = blockIdx.x;

    // ---- stage W1 fragments. W1[n] is [k=64][o=256] row-major.
    // A-frag (swapped GEMM1): lane (g,l15), elem j -> o = ht*16+l15, k = ks*32+g*8+j
    const float* W1n = w1g + (size_t)n * (BD * HID);
    #pragma unroll
    for (int i4 = 0; i4 < 4; ++i4) {
        int e  = i4 * 512 + tid;
        int ht = e >> 7;
        int ks = (e >> 6) & 1;
        int le = e & 63;
        int ge = le >> 4, oo = le & 15;
        f16x8 v;
        #pragma unroll
        for (int j = 0; j < 8; ++j)
            v[j] = (_Float16)W1n[(size_t)(ks * 32 + ge * 8 + j) * HID + ht * 16 + oo];
        *(f16x8*)&W1F[e * 8] = v;
    }

    // ---- stage W2 fragments (k-map k2(g,j) = (j>>2)*16 + g*4 + (j&3), matches a2 build)
    const float* W2n = w2g + (size_t)n * (HID * OD);
    #pragma unroll
    for (int i4 = 0; i4 < 4; ++i4) {
        int e  = i4 * 512 + tid;
        int p  = e >> 8;
        int n2 = (e >> 6) & 3;
        int le = e & 63;
        int ge = le >> 4, ce = le & 15;
        f16x8 v;
        #pragma unroll
        for (int j = 0; j < 8; ++j)
            v[j] = (_Float16)W2n[(size_t)(p * 32 + ((j >> 2) << 4) + ge * 4 + (j & 3)) * OD + n2 * 16 + ce];
        *(f16x8*)&W2L[e * 8] = v;
    }

    if (tid < HID) b1L[tid] = b1g[n * HID + tid];

    float b2b[4];
    #pragma unroll
    for (int n2 = 0; n2 < 4; ++n2) b2b[n2] = b2g[n * OD + n2 * 16 + l15];

    __syncthreads();   // only barrier

    const int wg_row0 = blockIdx.y * (SLABS * 256) + w * 32;
    const f32x4 z4 = {0.0f, 0.0f, 0.0f, 0.0f};

    // ---- prefetch slab 0 x rows (raw fp32)
    float4 pf[8];
    #pragma unroll
    for (int rs = 0; rs < 2; ++rs)
        #pragma unroll
        for (int ks = 0; ks < 2; ++ks) {
            const float* px = xg + (size_t)(wg_row0 + rs * 16 + l15) * IN_DIM + n * BD + ks * 32 + g * 8;
            pf[(rs * 2 + ks) * 2 + 0] = *(const float4*)px;
            pf[(rs * 2 + ks) * 2 + 1] = *(const float4*)(px + 4);
        }

    for (int s = 0; s < SLABS; ++s) {
        const int row0 = wg_row0 + s * 256;

        // convert prefetched fp32 -> f16 fragments
        f16x8 xa[2][2];
        #pragma unroll
        for (int rs = 0; rs < 2; ++rs)
            #pragma unroll
            for (int ks = 0; ks < 2; ++ks) {
                float4 lo = pf[(rs * 2 + ks) * 2 + 0];
                float4 hi = pf[(rs * 2 + ks) * 2 + 1];
                f16x8 v;
                v[0] = (_Float16)lo.x; v[1] = (_Float16)lo.y;
                v[2] = (_Float16)lo.z; v[3] = (_Float16)lo.w;
                v[4] = (_Float16)hi.x; v[5] = (_Float16)hi.y;
                v[6] = (_Float16)hi.z; v[7] = (_Float16)hi.w;
                xa[rs][ks] = v;
            }

        // issue next slab's loads (latency hides under this slab's compute)
        if (s + 1 < SLABS) {
            #pragma unroll
            for (int rs = 0; rs < 2; ++rs)
                #pragma unroll
                for (int ks = 0; ks < 2; ++ks) {
                    const float* px = xg + (size_t)(row0 + 256 + rs * 16 + l15) * IN_DIM + n * BD + ks * 32 + g * 8;
                    pf[(rs * 2 + ks) * 2 + 0] = *(const float4*)px;
                    pf[(rs * 2 + ks) * 2 + 1] = *(const float4*)(px + 4);
                }
        }

        f32x4 c2[2][4];
        #pragma unroll
        for (int rs = 0; rs < 2; ++rs)
            #pragma unroll
            for (int n2 = 0; n2 < 4; ++n2) c2[rs][n2] = z4;

        #pragma unroll
        for (int p = 0; p < 8; ++p) {
            // GEMM1 (swapped): lane holds S[batch=l15][hid = ht*16 + g*4+q]
            f32x4 c1[2][2];   // [htl][rs]
            #pragma unroll
            for (int htl = 0; htl < 2; ++htl) {
                f32x4 ca = z4, cb = z4;
                #pragma unroll
                for (int ks = 0; ks < 2; ++ks) {
                    f16x8 wf = *(const f16x8*)&W1F[((((p * 2 + htl) * 2) + ks) * 64 + l) * 8];
                    ca = __builtin_amdgcn_mfma_f32_16x16x32_f16(wf, xa[0][ks], ca, 0, 0, 0);
                    cb = __builtin_amdgcn_mfma_f32_16x16x32_f16(wf, xa[1][ks], cb, 0, 0, 0);
                }
                c1[htl][0] = ca; c1[htl][1] = cb;
            }
            // bias + gelu in registers -> A2 fragments (k2-map by construction)
            f32x4 b1a = *(const f32x4*)&b1L[(p * 2 + 0) * 16 + g * 4];
            f32x4 b1b = *(const f32x4*)&b1L[(p * 2 + 1) * 16 + g * 4];
            f16x8 a2[2];
            #pragma unroll
            for (int rs = 0; rs < 2; ++rs) {
                f16x8 v;
                #pragma unroll
                for (int q = 0; q < 4; ++q) {
                    v[q]     = (_Float16)gelu_f(c1[0][rs][q] + b1a[q]);
                    v[q + 4] = (_Float16)gelu_f(c1[1][rs][q] + b1b[q]);
                }
                a2[rs] = v;
            }
            // GEMM2 partial: K-slice p*32..p*32+31
            #pragma unroll
            for (int n2 = 0; n2 < 4; ++n2) {
                f16x8 bf = *(const f16x8*)&W2L[((p * 4 + n2) * 64 + l) * 8];
                c2[0][n2] = __builtin_amdgcn_mfma_f32_16x16x32_f16(a2[0], bf, c2[0][n2], 0, 0, 0);
                c2[1][n2] = __builtin_amdgcn_mfma_f32_16x16x32_f16(a2[1], bf, c2[1][n2], 0, 0, 0);
            }
        }

        // ---- epilogue: bias + fp32 store
        #pragma unroll
        for (int rs = 0; rs < 2; ++rs)
            #pragma unroll
            for (int n2 = 0; n2 < 4; ++n2)
                #pragma unroll
                for (int q = 0; q < 4; ++q) {
                    int row = row0 + rs * 16 + g * 4 + q;
                    outg[(size_t)row * IN_DIM + n * BD + n2 * 16 + l15] = c2[rs][n2][q] + b2b[n2];
                }
    }
}

extern "C" void kernel_launch(void* const* d_in, const int* in_sizes, int n_in,
                              void* d_out, int out_size, void* d_ws, size_t ws_size,
                              hipStream_t stream) {
    const float* x  = (const float*)d_in[0];
    const float* W1 = (const float*)d_in[1];
    const float* b1 = (const float*)d_in[2];
    const float* W2 = (const float*)d_in[3];
    const float* b2 = (const float*)d_in[4];
    float* out = (float*)d_out;

    dim3 grid(NB, GY, 1);
    dim3 block(512, 1, 1);
    hipLaunchKernelGGL(blockmlp_kernel, grid, block, 0, stream, x, W1, b1, W2, b2, out);
}

// Round 4
// 167.765 us; speedup vs baseline: 2.3919x; 2.3919x over previous
//
#include <hip/hip_runtime.h>

using f16x8 = _Float16 __attribute__((ext_vector_type(8)));
using f32x4 = float __attribute__((ext_vector_type(4)));

#define BS      8192
#define IN_DIM  4096
#define NB      64
#define BD      64
#define HID     256
#define OD      64
#define GY      16          // 1024 rows-of-grid: each WG (16 waves) covers 512 rows

__device__ __forceinline__ float gelu_f(float z) {
    // tanh-form GELU via exp2: z * (1 - 1/(exp2(2.302119*(z+0.044715 z^3)) + 1))
    float t = z * z;
    float p = __builtin_fmaf(0.044715f * z, t, z);
    float e = __builtin_amdgcn_exp2f(p * 2.3021193f);
    float r = __builtin_amdgcn_rcpf(e + 1.0f);
    return __builtin_fmaf(-z, r, z);
}

__global__ __launch_bounds__(1024, 8) void blockmlp_kernel(
    const float* __restrict__ xg, const float* __restrict__ w1g,
    const float* __restrict__ b1g, const float* __restrict__ w2g,
    const float* __restrict__ b2g, float* __restrict__ outg) {

    // Fragment-major weight LDS: entry e = tile*64 + lane, 8 f16 each.
    // Runtime reads are lane-linear ds_read_b128 (wave reads 1024 contiguous
    // bytes) -> zero bank conflicts (verified R3: SQ_LDS_BANK_CONFLICT = 0).
    __shared__ _Float16 W1F[2048 * 8];   // 32 KB  [ht=16][ks=2][lane][8]
    __shared__ _Float16 W2L[2048 * 8];   // 32 KB  [p=8][n2=4][lane][8]
    __shared__ float    b1L[HID];        // 1 KB

    const int tid = threadIdx.x;
    const int w   = tid >> 6;    // 0..15
    const int l   = tid & 63;
    const int g   = l >> 4;
    const int l15 = l & 15;
    const int n   = blockIdx.x;

    // ---- stage W1 fragments. W1[n] is [k=64][o=256] row-major.
    // A-frag (swapped GEMM1): lane (g,l15), elem j -> o = ht*16+l15, k = ks*32+g*8+j
    const float* W1n = w1g + (size_t)n * (BD * HID);
    #pragma unroll
    for (int i2 = 0; i2 < 2; ++i2) {
        int e  = i2 * 1024 + tid;
        int ht = e >> 7;
        int ks = (e >> 6) & 1;
        int le = e & 63;
        int ge = le >> 4, oo = le & 15;
        f16x8 v;
        #pragma unroll
        for (int j = 0; j < 8; ++j)
            v[j] = (_Float16)W1n[(size_t)(ks * 32 + ge * 8 + j) * HID + ht * 16 + oo];
        *(f16x8*)&W1F[e * 8] = v;
    }

    // ---- stage W2 fragments (k-map k2(g,j) = (j>>2)*16 + g*4 + (j&3), matches a2 build)
    const float* W2n = w2g + (size_t)n * (HID * OD);
    #pragma unroll
    for (int i2 = 0; i2 < 2; ++i2) {
        int e  = i2 * 1024 + tid;
        int p  = e >> 8;
        int n2 = (e >> 6) & 3;
        int le = e & 63;
        int ge = le >> 4, ce = le & 15;
        f16x8 v;
        #pragma unroll
        for (int j = 0; j < 8; ++j)
            v[j] = (_Float16)W2n[(size_t)(p * 32 + ((j >> 2) << 4) + ge * 4 + (j & 3)) * OD + n2 * 16 + ce];
        *(f16x8*)&W2L[e * 8] = v;
    }

    if (tid < HID) b1L[tid] = b1g[n * HID + tid];

    float b2b[4];
    #pragma unroll
    for (int n2 = 0; n2 < 4; ++n2) b2b[n2] = b2g[n * OD + n2 * 16 + l15];

    __syncthreads();   // only barrier

    const int row0 = blockIdx.y * 512 + w * 32;
    const f32x4 z4 = {0.0f, 0.0f, 0.0f, 0.0f};

    // ---- x fragments (B-operand of swapped GEMM1): x[row0+rs*16+l15][k=ks*32+g*8+j]
    f16x8 xa[2][2];
    #pragma unroll
    for (int rs = 0; rs < 2; ++rs)
        #pragma unroll
        for (int ks = 0; ks < 2; ++ks) {
            const float* px = xg + (size_t)(row0 + rs * 16 + l15) * IN_DIM + n * BD + ks * 32 + g * 8;
            float4 lo = *(const float4*)px;
            float4 hi = *(const float4*)(px + 4);
            f16x8 v;
            v[0] = (_Float16)lo.x; v[1] = (_Float16)lo.y;
            v[2] = (_Float16)lo.z; v[3] = (_Float16)lo.w;
            v[4] = (_Float16)hi.x; v[5] = (_Float16)hi.y;
            v[6] = (_Float16)hi.z; v[7] = (_Float16)hi.w;
            xa[rs][ks] = v;
        }

    f32x4 c2[2][4];
    #pragma unroll
    for (int rs = 0; rs < 2; ++rs)
        #pragma unroll
        for (int n2 = 0; n2 < 4; ++n2) c2[rs][n2] = z4;

    #pragma unroll
    for (int p = 0; p < 8; ++p) {
        // GEMM1 (swapped): lane holds S[batch=l15][hid = ht*16 + g*4 + q]
        f32x4 c1[2][2];   // [htl][rs]
        #pragma unroll
        for (int htl = 0; htl < 2; ++htl) {
            f32x4 ca = z4, cb = z4;
            #pragma unroll
            for (int ks = 0; ks < 2; ++ks) {
                f16x8 wf = *(const f16x8*)&W1F[((((p * 2 + htl) * 2) + ks) * 64 + l) * 8];
                ca = __builtin_amdgcn_mfma_f32_16x16x32_f16(wf, xa[0][ks], ca, 0, 0, 0);
                cb = __builtin_amdgcn_mfma_f32_16x16x32_f16(wf, xa[1][ks], cb, 0, 0, 0);
            }
            c1[htl][0] = ca; c1[htl][1] = cb;
        }
        // bias + gelu in registers -> A2 fragments (k2-map by construction)
        f32x4 b1a = *(const f32x4*)&b1L[(p * 2 + 0) * 16 + g * 4];
        f32x4 b1b = *(const f32x4*)&b1L[(p * 2 + 1) * 16 + g * 4];
        f16x8 a2[2];
        #pragma unroll
        for (int rs = 0; rs < 2; ++rs) {
            f16x8 v;
            #pragma unroll
            for (int q = 0; q < 4; ++q) {
                v[q]     = (_Float16)gelu_f(c1[0][rs][q] + b1a[q]);
                v[q + 4] = (_Float16)gelu_f(c1[1][rs][q] + b1b[q]);
            }
            a2[rs] = v;
        }
        // GEMM2 partial: K-slice p*32..p*32+31
        #pragma unroll
        for (int n2 = 0; n2 < 4; ++n2) {
            f16x8 bf = *(const f16x8*)&W2L[((p * 4 + n2) * 64 + l) * 8];
            c2[0][n2] = __builtin_amdgcn_mfma_f32_16x16x32_f16(a2[0], bf, c2[0][n2], 0, 0, 0);
            c2[1][n2] = __builtin_amdgcn_mfma_f32_16x16x32_f16(a2[1], bf, c2[1][n2], 0, 0, 0);
        }
    }

    // ---- epilogue: bias + fp32 store; n2 innermost so each row's 256-B slice
    // is completed by 4 consecutive 64-B store groups (write combining).
    #pragma unroll
    for (int rs = 0; rs < 2; ++rs)
        #pragma unroll
        for (int q = 0; q < 4; ++q) {
            int row = row0 + rs * 16 + g * 4 + q;
            float* po = outg + (size_t)row * IN_DIM + n * BD + l15;
            #pragma unroll
            for (int n2 = 0; n2 < 4; ++n2)
                po[n2 * 16] = c2[rs][n2][q] + b2b[n2];
        }
}

extern "C" void kernel_launch(void* const* d_in, const int* in_sizes, int n_in,
                              void* d_out, int out_size, void* d_ws, size_t ws_size,
                              hipStream_t stream) {
    const float* x  = (const float*)d_in[0];
    const float* W1 = (const float*)d_in[1];
    const float* b1 = (const float*)d_in[2];
    const float* W2 = (const float*)d_in[3];
    const float* b2 = (const float*)d_in[4];
    float* out = (float*)d_out;

    dim3 grid(NB, GY, 1);
    dim3 block(1024, 1, 1);
    hipLaunchKernelGGL(blockmlp_kernel, grid, block, 0, stream, x, W1, b1, W2, b2, out);
}

// Round 5
// 78.421 us; speedup vs baseline: 5.1170x; 2.1393x over previous
//
#include <hip/hip_runtime.h>

using f16x8 = _Float16 __attribute__((ext_vector_type(8)));
using f32x4 = float __attribute__((ext_vector_type(4)));

#define BS      8192
#define IN_DIM  4096
#define NB      64
#define BD      64
#define HID     256
#define OD      64
#define GY      32

__device__ __forceinline__ float gelu_f(float z) {
    // tanh-form GELU via exp2: z * (1 - 1/(exp2(2.302119*(z+0.044715 z^3)) + 1))
    float t = z * z;
    float p = __builtin_fmaf(0.044715f * z, t, z);
    float e = __builtin_amdgcn_exp2f(p * 2.3021193f);
    float r = __builtin_amdgcn_rcpf(e + 1.0f);
    return __builtin_fmaf(-z, r, z);
}

__global__ __launch_bounds__(512, 4) void blockmlp_kernel(
    const float* __restrict__ xg, const float* __restrict__ w1g,
    const float* __restrict__ b1g, const float* __restrict__ w2g,
    const float* __restrict__ b2g, float* __restrict__ outg) {

    // Fragment-major weight LDS (R3-verified): entry e = tile*64 + lane, 8 f16.
    // All runtime LDS ops (writes b128 and reads b128) are lane-linear: wave
    // touches 1024 contiguous bytes -> SQ_LDS_BANK_CONFLICT == 0.
    __shared__ _Float16 W1F[2048 * 8];   // 32 KB  [ht=16][ks=2][lane][8]
    __shared__ _Float16 W2L[2048 * 8];   // 32 KB  [p=8][n2=4][lane][8]
    __shared__ float    b1L[HID];        // 1 KB

    const int tid = threadIdx.x;
    const int w   = tid >> 6;
    const int l   = tid & 63;
    const int g   = l >> 4;
    const int l15 = l & 15;
    const int n   = blockIdx.x;

    // ---- stage W1 fragments. W1[n] is [k=64][o=256] row-major.
    // A-frag (swapped GEMM1): lane (g,l15), elem j -> o = ht*16+l15, k = ks*32+g*8+j
    const float* W1n = w1g + (size_t)n * (BD * HID);
    #pragma unroll
    for (int i4 = 0; i4 < 4; ++i4) {
        int e  = i4 * 512 + tid;
        int ht = e >> 7;
        int ks = (e >> 6) & 1;
        int le = e & 63;
        int ge = le >> 4, oo = le & 15;
        f16x8 v;
        #pragma unroll
        for (int j = 0; j < 8; ++j)
            v[j] = (_Float16)W1n[(size_t)(ks * 32 + ge * 8 + j) * HID + ht * 16 + oo];
        *(f16x8*)&W1F[e * 8] = v;
    }

    // ---- stage W2 fragments (k-map k2(g,j) = (j>>2)*16 + g*4 + (j&3), matches a2 build)
    const float* W2n = w2g + (size_t)n * (HID * OD);
    #pragma unroll
    for (int i4 = 0; i4 < 4; ++i4) {
        int e  = i4 * 512 + tid;
        int p  = e >> 8;
        int n2 = (e >> 6) & 3;
        int le = e & 63;
        int ge = le >> 4, ce = le & 15;
        f16x8 v;
        #pragma unroll
        for (int j = 0; j < 8; ++j)
            v[j] = (_Float16)W2n[(size_t)(p * 32 + ((j >> 2) << 4) + ge * 4 + (j & 3)) * OD + n2 * 16 + ce];
        *(f16x8*)&W2L[e * 8] = v;
    }

    if (tid < HID) b1L[tid] = b1g[n * HID + tid];

    float b2b[4];
    #pragma unroll
    for (int n2 = 0; n2 < 4; ++n2) b2b[n2] = b2g[n * OD + n2 * 16 + l15];

    __syncthreads();   // only barrier

    const int row0 = blockIdx.y * 256 + w * 32;

    // ---- x fragments (B-operand of swapped GEMM1): x[row0+rs*16+l15][k=ks*32+g*8+j]
    f16x8 xa[2][2];
    #pragma unroll
    for (int rs = 0; rs < 2; ++rs)
        #pragma unroll
        for (int ks = 0; ks < 2; ++ks) {
            const float* px = xg + (size_t)(row0 + rs * 16 + l15) * IN_DIM + n * BD + ks * 32 + g * 8;
            float4 lo = *(const float4*)px;
            float4 hi = *(const float4*)(px + 4);
            f16x8 v;
            v[0] = (_Float16)lo.x; v[1] = (_Float16)lo.y;
            v[2] = (_Float16)lo.z; v[3] = (_Float16)lo.w;
            v[4] = (_Float16)hi.x; v[5] = (_Float16)hi.y;
            v[6] = (_Float16)hi.z; v[7] = (_Float16)hi.w;
            xa[rs][ks] = v;
        }

    const f32x4 z4 = {0.0f, 0.0f, 0.0f, 0.0f};
    f32x4 c2[2][4];
    #pragma unroll
    for (int rs = 0; rs < 2; ++rs)
        #pragma unroll
        for (int n2 = 0; n2 < 4; ++n2) c2[rs][n2] = z4;

    #pragma unroll
    for (int p = 0; p < 8; ++p) {
        // GEMM1 (swapped): lane holds S[batch=l15][hid = ht*16 + g*4 + q]
        f32x4 c1[2][2];   // [htl][rs]
        #pragma unroll
        for (int htl = 0; htl < 2; ++htl) {
            f32x4 ca = z4, cb = z4;
            #pragma unroll
            for (int ks = 0; ks < 2; ++ks) {
                f16x8 wf = *(const f16x8*)&W1F[((((p * 2 + htl) * 2) + ks) * 64 + l) * 8];
                ca = __builtin_amdgcn_mfma_f32_16x16x32_f16(wf, xa[0][ks], ca, 0, 0, 0);
                cb = __builtin_amdgcn_mfma_f32_16x16x32_f16(wf, xa[1][ks], cb, 0, 0, 0);
            }
            c1[htl][0] = ca; c1[htl][1] = cb;
        }
        // bias + gelu in registers -> A2 fragments (k2-map by construction)
        f32x4 b1a = *(const f32x4*)&b1L[(p * 2 + 0) * 16 + g * 4];
        f32x4 b1b = *(const f32x4*)&b1L[(p * 2 + 1) * 16 + g * 4];
        f16x8 a2[2];
        #pragma unroll
        for (int rs = 0; rs < 2; ++rs) {
            f16x8 v;
            #pragma unroll
            for (int q = 0; q < 4; ++q) {
                v[q]     = (_Float16)gelu_f(c1[0][rs][q] + b1a[q]);
                v[q + 4] = (_Float16)gelu_f(c1[1][rs][q] + b1b[q]);
            }
            a2[rs] = v;
        }
        // GEMM2 partial: K-slice p*32..p*32+31
        #pragma unroll
        for (int n2 = 0; n2 < 4; ++n2) {
            f16x8 bf = *(const f16x8*)&W2L[((p * 4 + n2) * 64 + l) * 8];
            c2[0][n2] = __builtin_amdgcn_mfma_f32_16x16x32_f16(a2[0], bf, c2[0][n2], 0, 0, 0);
            c2[1][n2] = __builtin_amdgcn_mfma_f32_16x16x32_f16(a2[1], bf, c2[1][n2], 0, 0, 0);
        }
    }

    // ---- epilogue: bias + fp32 store (same order as R2)
    #pragma unroll
    for (int rs = 0; rs < 2; ++rs)
        #pragma unroll
        for (int n2 = 0; n2 < 4; ++n2)
            #pragma unroll
            for (int q = 0; q < 4; ++q) {
                int row = row0 + rs * 16 + g * 4 + q;
                outg[(size_t)row * IN_DIM + n * BD + n2 * 16 + l15] = c2[rs][n2][q] + b2b[n2];
            }
}

extern "C" void kernel_launch(void* const* d_in, const int* in_sizes, int n_in,
                              void* d_out, int out_size, void* d_ws, size_t ws_size,
                              hipStream_t stream) {
    const float* x  = (const float*)d_in[0];
    const float* W1 = (const float*)d_in[1];
    const float* b1 = (const float*)d_in[2];
    const float* W2 = (const float*)d_in[3];
    const float* b2 = (const float*)d_in[4];
    float* out = (float*)d_out;

    dim3 grid(NB, GY, 1);
    dim3 block(512, 1, 1);
    hipLaunchKernelGGL(blockmlp_kernel, grid, block, 0, stream, x, W1, b1, W2, b2, out);
}

// Round 6
// 77.648 us; speedup vs baseline: 5.1679x; 1.0100x over previous
//
#include <hip/hip_runtime.h>

using f16x8 = _Float16 __attribute__((ext_vector_type(8)));
using f32x4 = float __attribute__((ext_vector_type(4)));

#define BS      8192
#define IN_DIM  4096
#define NB      64
#define BD      64
#define HID     256
#define OD      64
#define GY      32

__device__ __forceinline__ float gelu_f(float z) {
    // tanh-form GELU via exp2: z * (1 - 1/(exp2(2.302119*(z+0.044715 z^3)) + 1))
    float t = z * z;
    float p = __builtin_fmaf(0.044715f * z, t, z);
    float e = __builtin_amdgcn_exp2f(p * 2.3021193f);
    float r = __builtin_amdgcn_rcpf(e + 1.0f);
    return __builtin_fmaf(-z, r, z);
}

// ---- prep: build fragment-major f16 weight images in d_ws (once per launch).
// W1 frag (A-op of swapped GEMM1), entry e: ht=e>>7, ks=(e>>6)&1, le=e&63:
//   elem j -> W1n[(ks*32+(le>>4)*8+j)*HID + (e>>7)*16 + (le&15)]
// W2 frag (B-op, k-map k2(g,j)=(j>>2)*16+g*4+(j&3)), entry e: p=e>>8, n2=(e>>6)&3.
__global__ __launch_bounds__(256) void prep_weights(
    const float* __restrict__ w1g, const float* __restrict__ w2g,
    f16x8* __restrict__ ws1, f16x8* __restrict__ ws2) {
    const int n = blockIdx.x;
    const int t = threadIdx.x;
    const float* W1n = w1g + (size_t)n * (BD * HID);
    const float* W2n = w2g + (size_t)n * (HID * OD);
    #pragma unroll
    for (int it = 0; it < 8; ++it) {
        int e = it * 256 + t;
        {
            int ht = e >> 7, ks = (e >> 6) & 1, le = e & 63;
            int ge = le >> 4, oo = le & 15;
            f16x8 v;
            #pragma unroll
            for (int j = 0; j < 8; ++j)
                v[j] = (_Float16)W1n[(size_t)(ks * 32 + ge * 8 + j) * HID + ht * 16 + oo];
            ws1[(size_t)n * 2048 + e] = v;
        }
        {
            int p = e >> 8, n2 = (e >> 6) & 3, le = e & 63;
            int ge = le >> 4, ce = le & 15;
            f16x8 v;
            #pragma unroll
            for (int j = 0; j < 8; ++j)
                v[j] = (_Float16)W2n[(size_t)(p * 32 + ((j >> 2) << 4) + ge * 4 + (j & 3)) * OD + n2 * 16 + ce];
            ws2[(size_t)n * 2048 + e] = v;
        }
    }
}

__global__ __launch_bounds__(512, 4) void blockmlp_kernel(
    const float* __restrict__ xg,
    const f16x8* __restrict__ ws1, const f16x8* __restrict__ ws2,
    const float* __restrict__ b1g, const float* __restrict__ b2g,
    float* __restrict__ outg) {

    // Fragment-major weight LDS (R3/R5-verified conflict-free): entry = tile*64+lane.
    __shared__ f16x8 W1F[2048];   // 32 KB  [ht=16][ks=2][lane]
    __shared__ f16x8 W2L[2048];   // 32 KB  [p=8][n2=4][lane]
    __shared__ float b1L[HID];    // 1 KB

    const int tid = threadIdx.x;
    const int w   = tid >> 6;
    const int l   = tid & 63;
    const int g   = l >> 4;
    const int l15 = l & 15;
    const int n   = blockIdx.x;

    // ---- stage prebuilt fragments: 8 coalesced 16-B loads, then 8 b128 LDS writes
    const f16x8* p1 = ws1 + (size_t)n * 2048;
    const f16x8* p2 = ws2 + (size_t)n * 2048;
    f16x8 s1[4], s2[4];
    #pragma unroll
    for (int it = 0; it < 4; ++it) { s1[it] = p1[it * 512 + tid]; }
    #pragma unroll
    for (int it = 0; it < 4; ++it) { s2[it] = p2[it * 512 + tid]; }
    #pragma unroll
    for (int it = 0; it < 4; ++it) { W1F[it * 512 + tid] = s1[it]; }
    #pragma unroll
    for (int it = 0; it < 4; ++it) { W2L[it * 512 + tid] = s2[it]; }

    if (tid < HID) b1L[tid] = b1g[n * HID + tid];

    float b2b[4];
    #pragma unroll
    for (int n2 = 0; n2 < 4; ++n2) b2b[n2] = b2g[n * OD + n2 * 16 + l15];

    __syncthreads();   // only barrier

    const int row0 = blockIdx.y * 256 + w * 32;

    // ---- x fragments (B-operand of swapped GEMM1): x[row0+rs*16+l15][k=ks*32+g*8+j]
    f16x8 xa[2][2];
    #pragma unroll
    for (int rs = 0; rs < 2; ++rs)
        #pragma unroll
        for (int ks = 0; ks < 2; ++ks) {
            const float* px = xg + (size_t)(row0 + rs * 16 + l15) * IN_DIM + n * BD + ks * 32 + g * 8;
            float4 lo = *(const float4*)px;
            float4 hi = *(const float4*)(px + 4);
            f16x8 v;
            v[0] = (_Float16)lo.x; v[1] = (_Float16)lo.y;
            v[2] = (_Float16)lo.z; v[3] = (_Float16)lo.w;
            v[4] = (_Float16)hi.x; v[5] = (_Float16)hi.y;
            v[6] = (_Float16)hi.z; v[7] = (_Float16)hi.w;
            xa[rs][ks] = v;
        }

    const f32x4 z4 = {0.0f, 0.0f, 0.0f, 0.0f};
    f32x4 c2[2][4];
    #pragma unroll
    for (int rs = 0; rs < 2; ++rs)
        #pragma unroll
        for (int n2 = 0; n2 < 4; ++n2) c2[rs][n2] = z4;

    #pragma unroll
    for (int p = 0; p < 8; ++p) {
        // GEMM1 (swapped): lane holds S[batch=l15][hid = ht*16 + g*4 + q]
        f32x4 c1[2][2];   // [htl][rs]
        #pragma unroll
        for (int htl = 0; htl < 2; ++htl) {
            f32x4 ca = z4, cb = z4;
            #pragma unroll
            for (int ks = 0; ks < 2; ++ks) {
                f16x8 wf = W1F[(((p * 2 + htl) * 2) + ks) * 64 + l];
                ca = __builtin_amdgcn_mfma_f32_16x16x32_f16(wf, xa[0][ks], ca, 0, 0, 0);
                cb = __builtin_amdgcn_mfma_f32_16x16x32_f16(wf, xa[1][ks], cb, 0, 0, 0);
            }
            c1[htl][0] = ca; c1[htl][1] = cb;
        }
        // bias + gelu in registers -> A2 fragments (k2-map by construction)
        f32x4 b1a = *(const f32x4*)&b1L[(p * 2 + 0) * 16 + g * 4];
        f32x4 b1b = *(const f32x4*)&b1L[(p * 2 + 1) * 16 + g * 4];
        f16x8 a2[2];
        #pragma unroll
        for (int rs = 0; rs < 2; ++rs) {
            f16x8 v;
            #pragma unroll
            for (int q = 0; q < 4; ++q) {
                v[q]     = (_Float16)gelu_f(c1[0][rs][q] + b1a[q]);
                v[q + 4] = (_Float16)gelu_f(c1[1][rs][q] + b1b[q]);
            }
            a2[rs] = v;
        }
        // GEMM2 partial: K-slice p*32..p*32+31
        #pragma unroll
        for (int n2 = 0; n2 < 4; ++n2) {
            f16x8 bf = W2L[(p * 4 + n2) * 64 + l];
            c2[0][n2] = __builtin_amdgcn_mfma_f32_16x16x32_f16(a2[0], bf, c2[0][n2], 0, 0, 0);
            c2[1][n2] = __builtin_amdgcn_mfma_f32_16x16x32_f16(a2[1], bf, c2[1][n2], 0, 0, 0);
        }
    }

    // ---- epilogue: bias + fp32 store
    #pragma unroll
    for (int rs = 0; rs < 2; ++rs)
        #pragma unroll
        for (int n2 = 0; n2 < 4; ++n2)
            #pragma unroll
            for (int q = 0; q < 4; ++q) {
                int row = row0 + rs * 16 + g * 4 + q;
                outg[(size_t)row * IN_DIM + n * BD + n2 * 16 + l15] = c2[rs][n2][q] + b2b[n2];
            }
}

extern "C" void kernel_launch(void* const* d_in, const int* in_sizes, int n_in,
                              void* d_out, int out_size, void* d_ws, size_t ws_size,
                              hipStream_t stream) {
    const float* x  = (const float*)d_in[0];
    const float* W1 = (const float*)d_in[1];
    const float* b1 = (const float*)d_in[2];
    const float* W2 = (const float*)d_in[3];
    const float* b2 = (const float*)d_in[4];
    float* out = (float*)d_out;

    f16x8* ws1 = (f16x8*)d_ws;            // 64*2048*16 B = 2 MB
    f16x8* ws2 = ws1 + (size_t)NB * 2048; // +2 MB  (ws_size must be >= 4 MB)

    hipLaunchKernelGGL(prep_weights, dim3(NB), dim3(256), 0, stream, W1, W2, ws1, ws2);
    hipLaunchKernelGGL(blockmlp_kernel, dim3(NB, GY), dim3(512), 0, stream,
                       x, ws1, ws2, b1, b2, out);
}